// Round 5
// baseline (1338.083 us; speedup 1.0000x reference)
//
#include <hip/hip_runtime.h>

// ---------------------------------------------------------------------------
// update_v (PDN-GNN) on MI355X / gfx950.  All float I/O fp32.
//
// R5 changes vs R4 (passed, 1280 us, absmax 3.66e-4):
//  - No fp32 atomics anywhere: deg/dinv computed from CSR by k_deg; edge
//    norm computed on the fly in k_gather (dinv[row]*ew*dinv[col]).
//  - Fused: cntm into k_edge, scatter_m into k_scatter, scanA/scanC via
//    gridDim.y=2, 4x splitw into one kernel.
//  - Final 256->1 dot folded into last GEMM epilogue (shfl-reduce within
//    16-lane row groups + atomicAdd to zeroed d_out). s1 round-trip for the
//    last layer eliminated.
//  - GEMM core unchanged from R4 (global_load_lds width=16, 3-term split
//    MFMA AhWh+AlWh+AhWl ~ fp32 exact).
//
// Workspace layout (bytes) — flat, no aliasing (~223 MB of ~1.23 GB ws):
//   edgep  0            12,800,000   (int2: row, ew-bits; CSR by col)
//   ew     12,800,000    6,400,000
//   midx   19,200,000    2,400,000
//   cntC   21,600,000      200,000 \  memset together
//   cntM   21,800,000      200,000 /
//   offC   22,200,000      200,004
//   curC   22,400,256      200,000
//   offM   22,600,256      200,004
//   curM   22,800,512      200,000
//   dinv   23,000,512      200,000
//   Wh     23,200,512      532,480
//   Wl     23,732,992      532,480
//   partC  24,265,472          784
//   partM  24,266,368          784
//   XcatH  24,268,800   16,000,000   (50000 x 160 u16)
//   XcatL  40,268,800   16,000,000
//   v1h    56,268,800   12,800,000
//   v1l    69,068,800   12,800,000
//   xw     81,868,800   12,800,000   (single bf16 plane)
//   gh     94,668,800   12,800,000
//   gl    107,468,800   12,800,000
//   s0h   120,268,800   25,600,000
//   s0l   145,868,800   25,600,000
//   s1h   171,468,800   25,600,000
//   s1l   197,068,800   25,600,000
// ---------------------------------------------------------------------------

#define Nn 50000
#define Mm 600000
#define Ee 1600000
#define NB 196          // ceil(Nn/256)

typedef unsigned short u16;
typedef unsigned int u32;
typedef __attribute__((ext_vector_type(8))) short bh8;   // 8 bf16 = 4 VGPRs
typedef __attribute__((ext_vector_type(4))) float f4;    // 4 fp32 acc

__device__ __forceinline__ float bf2f(u16 u) {
    union { u32 i; float f; } v; v.i = ((u32)u) << 16; return v.f;
}
__device__ __forceinline__ u16 f2bf(float f) {   // RNE, finite inputs
    union { float f; u32 u; } v; v.f = f;
    return (u16)((v.u + 0x7fffu + ((v.u >> 16) & 1u)) >> 16);
}

// global -> LDS direct copy, 16 B per lane (m97 pattern, width=16)
#define GLD16(gp, lp)                                                         \
    __builtin_amdgcn_global_load_lds(                                         \
        (const __attribute__((address_space(1))) unsigned int*)(gp),          \
        (__attribute__((address_space(3))) unsigned int*)(lp), 16, 0, 0)

// ------------------- edge MLP + histograms (int atomics only) --------------
__global__ __launch_bounds__(256) void k_edge(
    const float* __restrict__ attr, const int* __restrict__ eidx,
    const int* __restrict__ ii,
    const float* __restrict__ w1, const float* __restrict__ b1,
    const float* __restrict__ w2, const float* __restrict__ b2,
    float* __restrict__ ew, int* __restrict__ cntC, int* __restrict__ cntM)
{
    __shared__ float sW1[64], sB1[8], sW2[8], sB2;
    int t = threadIdx.x;
    if (t < 64) sW1[t] = w1[t];
    if (t < 8) { sB1[t] = b1[t]; sW2[t] = w2[t]; }
    if (t == 0) sB2 = b2[0];
    __syncthreads();
    int e = blockIdx.x * 256 + t;
    if (e < Mm) atomicAdd(&cntM[ii[e]], 1);        // fused message histogram
    if (e >= Ee) return;
    float4 q0 = *(const float4*)(attr + (size_t)e * 8);
    float4 q1 = *(const float4*)(attr + (size_t)e * 8 + 4);
    float a[8] = { q0.x, q0.y, q0.z, q0.w, q1.x, q1.y, q1.z, q1.w };
    float z = sB2;
#pragma unroll
    for (int j = 0; j < 8; ++j) {
        float h = sB1[j];
#pragma unroll
        for (int k = 0; k < 8; ++k) h += a[k] * sW1[j * 8 + k];
        z += fmaxf(h, 0.f) * sW2[j];
    }
    ew[e] = 1.f / (1.f + __expf(-z));
    atomicAdd(&cntC[eidx[Ee + e]], 1);
}

// --------------- 3-phase multi-block exclusive scan (y = C/M) --------------
__global__ __launch_bounds__(256) void k_scanA(
    const int* __restrict__ cntC_, int* __restrict__ locC, int* __restrict__ partC_,
    const int* __restrict__ cntM_, int* __restrict__ locM, int* __restrict__ partM_)
{
    const int* cnt = blockIdx.y ? cntM_ : cntC_;
    int* loc  = blockIdx.y ? locM : locC;
    int* part = blockIdx.y ? partM_ : partC_;
    __shared__ int buf[256];
    int t = threadIdx.x, i = blockIdx.x * 256 + t;
    int v = (i < Nn) ? cnt[i] : 0;
    buf[t] = v;
    __syncthreads();
#pragma unroll
    for (int d = 1; d < 256; d <<= 1) {
        int x = (t >= d) ? buf[t - d] : 0;
        __syncthreads();
        buf[t] += x;
        __syncthreads();
    }
    if (i < Nn) loc[i] = buf[t] - v;        // local exclusive
    if (t == 255) part[blockIdx.x] = buf[255];
}

__global__ __launch_bounds__(256) void k_scanB(int* __restrict__ pA,
                                               int* __restrict__ pB)
{
    int* p = blockIdx.x ? pB : pA;
    __shared__ int buf[256];
    int t = threadIdx.x;
    int v = (t < NB) ? p[t] : 0;
    buf[t] = v;
    __syncthreads();
#pragma unroll
    for (int d = 1; d < 256; d <<= 1) {
        int x = (t >= d) ? buf[t - d] : 0;
        __syncthreads();
        buf[t] += x;
        __syncthreads();
    }
    if (t < NB) p[t] = buf[t] - v;
}

__global__ __launch_bounds__(256) void k_scanC(
    const int* __restrict__ cntC_, const int* __restrict__ partC_,
    int* __restrict__ offC_, int* __restrict__ curC_,
    const int* __restrict__ cntM_, const int* __restrict__ partM_,
    int* __restrict__ offM_, int* __restrict__ curM_)
{
    const int* cnt  = blockIdx.y ? cntM_ : cntC_;
    const int* part = blockIdx.y ? partM_ : partC_;
    int* off = blockIdx.y ? offM_ : offC_;
    int* cur = blockIdx.y ? curM_ : curC_;
    int t = threadIdx.x, i = blockIdx.x * 256 + t;
    if (i >= Nn) return;
    int v = off[i] + part[blockIdx.x];
    off[i] = v;
    cur[i] = v;
    if (i == Nn - 1) off[Nn] = v + cnt[i];
}

// --------------------- CSR scatter (edges + messages fused) ----------------
__global__ __launch_bounds__(256) void k_scatter(
    const int* __restrict__ eidx, const float* __restrict__ ew,
    const int* __restrict__ ii, int* __restrict__ curC,
    int* __restrict__ curM, int2* __restrict__ edgep, int* __restrict__ midx)
{
    int e = blockIdx.x * 256 + threadIdx.x;
    if (e < Mm) midx[atomicAdd(&curM[ii[e]], 1)] = e;
    if (e >= Ee) return;
    int r = eidx[e];
    float w = ew[e];
    int idx = atomicAdd(&curC[eidx[Ee + e]], 1);
    edgep[idx] = make_int2(r, __float_as_int(w));
}

// ------------------ deg/dinv from CSR (no atomics, coalesced) --------------
__global__ __launch_bounds__(256) void k_deg(
    const int* __restrict__ offC, const int2* __restrict__ edgep,
    float* __restrict__ dinv)
{
    int wv = threadIdx.x >> 6, lane = threadIdx.x & 63;
    int n = blockIdx.x * 4 + wv;
    if (n >= Nn) return;
    int j0 = offC[n], j1 = offC[n + 1];
    float s = 0.f;
    for (int j = j0 + lane; j < j1; j += 64)
        s += __int_as_float(edgep[j].y);
#pragma unroll
    for (int d = 32; d >= 1; d >>= 1) s += __shfl_xor(s, d, 64);
    if (lane == 0)
        dinv[n] = (s > 0.f) ? rsqrtf(fmaxf(s, 1e-30f)) : 0.f;
}

// --------------------------- e2 segment sum -> Xcat hi/lo planes -----------
__global__ __launch_bounds__(256) void k_segsum(
    const int* __restrict__ offM, const int* __restrict__ midx,
    const float* __restrict__ e2, const float* __restrict__ afe,
    u16* __restrict__ XH, u16* __restrict__ XL)
{
    int wv = threadIdx.x >> 6, lane = threadIdx.x & 63;
    int n = blockIdx.x * 4 + wv;
    if (n >= Nn) return;
    int j0 = offM[n], j1 = offM[n + 1];
    float a0 = 0.f, a1 = 0.f;
    int j = j0;
    if (j < j1) {
        int m = midx[j];
        float2 p = *(const float2*)(e2 + (size_t)m * 128 + lane * 2);
        for (++j; j < j1; ++j) {
            int m2 = midx[j];
            float2 p2 = *(const float2*)(e2 + (size_t)m2 * 128 + lane * 2);
            a0 += p.x; a1 += p.y;
            p = p2;
        }
        a0 += p.x; a1 += p.y;
    }
    u16 h0 = f2bf(a0), h1 = f2bf(a1);
    u16 l0 = f2bf(a0 - bf2f(h0)), l1 = f2bf(a1 - bf2f(h1));
    *(u32*)&XH[(size_t)n * 160 + lane * 2] = (u32)h0 | ((u32)h1 << 16);
    *(u32*)&XL[(size_t)n * 160 + lane * 2] = (u32)l0 | ((u32)l1 << 16);
    if (lane < 32) {                       // channels 128..159: afe then pad 0
        int ch = 128 + lane;
        float v = (ch < 135) ? afe[(size_t)n * 7 + (ch - 128)] : 0.f;
        u16 h = f2bf(v);
        XH[(size_t)n * 160 + ch] = h;
        XL[(size_t)n * 160 + ch] = f2bf(v - bf2f(h));
    }
}

// ---------------- all weights: fp32 -> bf16 hi+lo (one dispatch) -----------
// Wh/Wl element map: [0,20480) lin_v padded 135->160; [20480,36864) conv;
// [36864,69632) lin_up; [69632,266240) lins (3 x 256 x 256).
__global__ __launch_bounds__(256) void k_splitw(
    const float* __restrict__ lin_v_w, const float* __restrict__ conv_w,
    const float* __restrict__ lin_up_w, const float* __restrict__ lins_w,
    u16* __restrict__ h, u16* __restrict__ l)
{
    int idx = blockIdx.x * 256 + threadIdx.x;
    if (idx >= 266240) return;
    float x;
    if (idx < 20480) {
        int r = idx / 160, c = idx % 160;
        x = (c < 135) ? lin_v_w[(size_t)r * 135 + c] : 0.f;
    } else if (idx < 36864) {
        x = conv_w[idx - 20480];
    } else if (idx < 69632) {
        x = lin_up_w[idx - 36864];
    } else {
        x = lins_w[idx - 69632];
    }
    u16 hh = f2bf(x);
    h[idx] = hh;
    l[idx] = f2bf(x - bf2f(hh));
}

// --------------------------- split MFMA GEMM -------------------------------
// Y = op(X @ W^T + bias); X,W as bf16 hi/lo planes [rows][K] u16.
// acc += Ah*Wh + Al*Wh + Ah*Wl (~fp32, err ~2^-17).
// Tile 128x128, BK=32, 4 waves (2x2 of 64x64), 16x16x32 MFMA; staging via
// global_load_lds width=16 into packed [128][32] u16 planes (wave wv stages
// plane wv). Layouts (m89/m91): A lane = A[m=lane&15][k=(lane>>4)*8+j];
// D: col=lane&15, row=(lane>>4)*4+r.
// flags: 1=relu, 2=single-bf16 out (Yh only), 4=dot epilogue (w/ lw -> dout).
__global__ __launch_bounds__(256) void k_gemm(
    const u16* __restrict__ Ah, const u16* __restrict__ Al,
    const u16* __restrict__ Bh, const u16* __restrict__ Bl,
    const float* __restrict__ bias, u16* __restrict__ Yh, u16* __restrict__ Yl,
    const float* __restrict__ lw, float* __restrict__ dout,
    int M, int K, int NO, int flags)
{
    __shared__ __align__(16) u16 sT[4][128 * 32];   // Ah, Al, Bh, Bl: 32 KB
    const int t = threadIdx.x;
    const int m0 = blockIdx.x * 128, n0 = blockIdx.y * 128;
    const int lane = t & 63, wv = t >> 6;
    const int wm = (wv >> 1) * 64, wn = (wv & 1) * 64;
    const int lr = lane & 15, lq = lane >> 4;
    const u16* gplane = (wv == 0) ? Ah : (wv == 1) ? Al : (wv == 2) ? Bh : Bl;
    u16* lplane = &sT[wv][0];
    const int rbase = (wv < 2) ? m0 : n0;
    const int rlim = (wv < 2) ? (M - 1) : 0x7fffffff;
    const int srow = lane >> 2;            // 0..15 within 16-row group
    const int scol = (lane & 3) * 8;       // u16 chunk offset
    f4 acc[4][4] = {};

    for (int k0 = 0; k0 < K; k0 += 32) {
        __syncthreads();                   // prev frag reads done
#pragma unroll
        for (int i = 0; i < 8; ++i) {
            int grow = rbase + i * 16 + srow;
            if (grow > rlim) grow = rlim;  // clamp (dup rows, discarded)
            const u16* gp = gplane + (size_t)grow * K + k0 + scol;
            GLD16(gp, lplane + i * 512);
        }
        __syncthreads();                   // vmcnt(0) drains the LDS-DMA
        bh8 fah[4], fal[4], fbh[4], fbl[4];
#pragma unroll
        for (int i = 0; i < 4; ++i) {
            fah[i] = *(const bh8*)&sT[0][(wm + i * 16 + lr) * 32 + lq * 8];
            fal[i] = *(const bh8*)&sT[1][(wm + i * 16 + lr) * 32 + lq * 8];
            fbh[i] = *(const bh8*)&sT[2][(wn + i * 16 + lr) * 32 + lq * 8];
            fbl[i] = *(const bh8*)&sT[3][(wn + i * 16 + lr) * 32 + lq * 8];
        }
#pragma unroll
        for (int mi = 0; mi < 4; ++mi)
#pragma unroll
            for (int ni = 0; ni < 4; ++ni) {
                acc[mi][ni] = __builtin_amdgcn_mfma_f32_16x16x32_bf16(
                    fah[mi], fbh[ni], acc[mi][ni], 0, 0, 0);
                acc[mi][ni] = __builtin_amdgcn_mfma_f32_16x16x32_bf16(
                    fal[mi], fbh[ni], acc[mi][ni], 0, 0, 0);
                acc[mi][ni] = __builtin_amdgcn_mfma_f32_16x16x32_bf16(
                    fah[mi], fbl[ni], acc[mi][ni], 0, 0, 0);
            }
    }

    if (flags & 4) {                       // fused relu + 256->1 dot epilogue
        float bb[4], wl4[4];
#pragma unroll
        for (int ni = 0; ni < 4; ++ni) {
            int gn = n0 + wn + ni * 16 + lr;
            bb[ni] = bias[gn];
            wl4[ni] = lw[gn];
        }
#pragma unroll
        for (int mi = 0; mi < 4; ++mi) {
#pragma unroll
            for (int r = 0; r < 4; ++r) {
                int gm = m0 + wm + mi * 16 + lq * 4 + r;
                float sdot = 0.f;
#pragma unroll
                for (int ni = 0; ni < 4; ++ni)
                    sdot += fmaxf(acc[mi][ni][r] + bb[ni], 0.f) * wl4[ni];
                sdot += __shfl_xor(sdot, 1, 64);   // reduce within 16-lane
                sdot += __shfl_xor(sdot, 2, 64);   // row group (lr bits)
                sdot += __shfl_xor(sdot, 4, 64);
                sdot += __shfl_xor(sdot, 8, 64);
                if (lr == 0 && gm < M) atomicAdd(dout + gm, sdot);
            }
        }
        return;
    }

#pragma unroll
    for (int ni = 0; ni < 4; ++ni) {
        int gn = n0 + wn + ni * 16 + lr;
        float bv = bias ? bias[gn] : 0.f;
#pragma unroll
        for (int mi = 0; mi < 4; ++mi) {
#pragma unroll
            for (int r = 0; r < 4; ++r) {
                int gm = m0 + wm + mi * 16 + lq * 4 + r;
                if (gm < M) {
                    float v = acc[mi][ni][r] + bv;
                    if (flags & 1) v = fmaxf(v, 0.f);
                    u16 h = f2bf(v);
                    Yh[(size_t)gm * NO + gn] = h;
                    if (!(flags & 2))
                        Yl[(size_t)gm * NO + gn] = f2bf(v - bf2f(h));
                }
            }
        }
    }
}

// --------------------------- conv gather (CSR by col) ----------------------
// wave-per-node; norm = dinv[row]*ew*dinv[n] computed on the fly; depth-2
// pipelined (edgep -> {xw row, dinv[row]}).
__global__ __launch_bounds__(256) void k_gather(
    const int* __restrict__ off, const int2* __restrict__ edgep,
    const float* __restrict__ dinv, const u16* __restrict__ xw,
    u16* __restrict__ OH, u16* __restrict__ OL, int relu)
{
    int wv = threadIdx.x >> 6, lane = threadIdx.x & 63;
    int n = blockIdx.x * 4 + wv;
    if (n >= Nn) return;
    int j0 = off[n], j1 = off[n + 1];
    float dn = dinv[n];
    float a0 = 0.f, a1 = 0.f;
    int j = j0;
    if (j < j1) {
        int2 ep = edgep[j];
        u32 p = *(const u32*)(xw + (size_t)ep.x * 128 + lane * 2);
        float dr = dinv[ep.x];
        for (++j; j < j1; ++j) {
            int2 ep2 = edgep[j];
            u32 p2 = *(const u32*)(xw + (size_t)ep2.x * 128 + lane * 2);
            float dr2 = dinv[ep2.x];
            float w = dr * __int_as_float(ep.y) * dn;
            a0 += w * bf2f((u16)(p & 0xffff));
            a1 += w * bf2f((u16)(p >> 16));
            ep = ep2; p = p2; dr = dr2;
        }
        float w = dr * __int_as_float(ep.y) * dn;
        a0 += w * bf2f((u16)(p & 0xffff));
        a1 += w * bf2f((u16)(p >> 16));
    }
    if (relu) { a0 = fmaxf(a0, 0.f); a1 = fmaxf(a1, 0.f); }
    u16 h0 = f2bf(a0), h1 = f2bf(a1);
    u16 l0 = f2bf(a0 - bf2f(h0)), l1 = f2bf(a1 - bf2f(h1));
    *(u32*)&OH[(size_t)n * 128 + lane * 2] = (u32)h0 | ((u32)h1 << 16);
    *(u32*)&OL[(size_t)n * 128 + lane * 2] = (u32)l0 | ((u32)l1 << 16);
}

// ---------------------------------------------------------------------------
extern "C" void kernel_launch(void* const* d_in, const int* in_sizes, int n_in,
                              void* d_out, int out_size, void* d_ws, size_t ws_size,
                              hipStream_t stream)
{
    (void)in_sizes; (void)n_in; (void)out_size; (void)ws_size;
    const float* e2       = (const float*)d_in[0];
    const int*   iidx     = (const int*)d_in[1];
    const float* afe      = (const float*)d_in[2];
    const int*   bei      = (const int*)d_in[3];
    const float* battr    = (const float*)d_in[4];
    const float* lin_v_w  = (const float*)d_in[5];
    const float* lin_v_b  = (const float*)d_in[6];
    const float* conv_w   = (const float*)d_in[7];
    const float* w1       = (const float*)d_in[8];
    const float* b1       = (const float*)d_in[9];
    const float* w2       = (const float*)d_in[10];
    const float* b2       = (const float*)d_in[11];
    const float* lin_up_w = (const float*)d_in[12];
    const float* lin_up_b = (const float*)d_in[13];
    const float* lins_w   = (const float*)d_in[14];
    const float* lins_b   = (const float*)d_in[15];
    const float* lin_w    = (const float*)d_in[16];

    char* ws = (char*)d_ws;
    int2*  edgep = (int2*) (ws + 0);
    float* ew    = (float*)(ws + 12800000);
    int*   midx  = (int*)  (ws + 19200000);
    int*   cntC  = (int*)  (ws + 21600000);
    int*   cntM  = (int*)  (ws + 21800000);
    int*   offC  = (int*)  (ws + 22200000);
    int*   curC  = (int*)  (ws + 22400256);
    int*   offM  = (int*)  (ws + 22600256);
    int*   curM  = (int*)  (ws + 22800512);
    float* dinv  = (float*)(ws + 23000512);
    u16*   Wh    = (u16*)  (ws + 23200512);     // 266,240 elements
    u16*   Wl    = (u16*)  (ws + 23732992);
    int*   partC = (int*)  (ws + 24265472);
    int*   partM = (int*)  (ws + 24266368);
    u16*   XcatH = (u16*)  (ws + 24268800);
    u16*   XcatL = (u16*)  (ws + 40268800);
    u16*   v1h   = (u16*)  (ws + 56268800);
    u16*   v1l   = (u16*)  (ws + 69068800);
    u16*   xw    = (u16*)  (ws + 81868800);
    u16*   gh    = (u16*)  (ws + 94668800);
    u16*   gl    = (u16*)  (ws + 107468800);
    u16*   s0h   = (u16*)  (ws + 120268800);
    u16*   s0l   = (u16*)  (ws + 145868800);
    u16*   s1h   = (u16*)  (ws + 171468800);
    u16*   s1l   = (u16*)  (ws + 197068800);

    const int oWv = 0, oConv = 20480, oLup = 36864, oLins = 69632;

    hipMemsetAsync(ws + 21600000, 0, 400000, stream);        // cntC, cntM
    hipMemsetAsync(d_out, 0, (size_t)Nn * 4, stream);        // dot accumulator

    k_edge<<<(Ee + 255) / 256, 256, 0, stream>>>(battr, bei, iidx,
                                                 w1, b1, w2, b2,
                                                 ew, cntC, cntM);
    k_scanA<<<dim3(NB, 2), 256, 0, stream>>>(cntC, offC, partC,
                                             cntM, offM, partM);
    k_scanB<<<2, 256, 0, stream>>>(partC, partM);
    k_scanC<<<dim3(NB, 2), 256, 0, stream>>>(cntC, partC, offC, curC,
                                             cntM, partM, offM, curM);
    k_scatter<<<(Ee + 255) / 256, 256, 0, stream>>>(bei, ew, iidx, curC,
                                                    curM, edgep, midx);
    k_deg<<<(Nn + 3) / 4, 256, 0, stream>>>(offC, edgep, dinv);
    k_segsum<<<(Nn + 3) / 4, 256, 0, stream>>>(offM, midx, e2, afe,
                                               XcatH, XcatL);
    k_splitw<<<(266240 + 255) / 256, 256, 0, stream>>>(
        lin_v_w, conv_w, lin_up_w, lins_w, Wh, Wl);

#define GEMM(XH, XL, WO, Bp, YH, YL, LW, DO, M_, K_, NO_, FL_)                \
    k_gemm<<<dim3(((M_) + 127) / 128, (NO_) / 128), 256, 0, stream>>>(        \
        XH, XL, Wh + (WO), Wl + (WO), (const float*)(Bp), YH, YL,             \
        LW, DO, M_, K_, NO_, FL_)

    GEMM(XcatH, XcatL, oWv, lin_v_b, v1h, v1l, nullptr, nullptr,
         Nn, 160, 128, 0);
    GEMM(v1h, v1l, oConv, nullptr, xw, nullptr, nullptr, nullptr,
         Nn, 128, 128, 2);
    k_gather<<<(Nn + 3) / 4, 256, 0, stream>>>(offC, edgep, dinv, xw,
                                               gh, gl, 0);
    GEMM(gh, gl, oConv, nullptr, xw, nullptr, nullptr, nullptr,
         Nn, 128, 128, 2);
    k_gather<<<(Nn + 3) / 4, 256, 0, stream>>>(offC, edgep, dinv, xw,
                                               gh, gl, 1);
    GEMM(gh, gl, oLup, lin_up_b, s0h, s0l, nullptr, nullptr,
         Nn, 128, 256, 0);
    GEMM(s0h, s0l, oLins + 0 * 65536, lins_b + 0, s1h, s1l, nullptr, nullptr,
         Nn, 256, 256, 1);
    GEMM(s1h, s1l, oLins + 1 * 65536, lins_b + 256, s0h, s0l, nullptr, nullptr,
         Nn, 256, 256, 1);
    GEMM(s0h, s0l, oLins + 2 * 65536, lins_b + 512, xw, nullptr,
         lin_w, (float*)d_out, Nn, 256, 256, 1 | 4);
#undef GEMM
}